// Round 17
// baseline (35.347 us; speedup 1.0000x reference)
//
#include <hip/hip_runtime.h>
#include <hip/hip_bf16.h>

#define NUM_C  16
#define NUM_D  8
#define RECEPT 512
#define LROW   32768
#define EPS_V  1e-4f

// per-block x slice: 64 windows * 256 stride + 256 overlap = 16640 bf16
// = 33280 B; +headroom for xsw (sets bits 4-6) -> 33536
#define XBYTES 33536

typedef __attribute__((ext_vector_type(8))) short short8;
typedef __attribute__((ext_vector_type(4))) float f32x4;

__device__ __forceinline__ unsigned short f2bf(float f) {
    unsigned int u = __builtin_bit_cast(unsigned int, f);
    u += 0x7fffu + ((u >> 16) & 1u);   // round-to-nearest-even
    return (unsigned short)(u >> 16);
}

// XOR swizzle on byte address in the bf16 x LDS slice (involution; applied on
// both staging writes and A-fragment reads; breaks the 512B window stride).
// Only touches bits 4-6 -> never crosses a 128B line boundary.
__device__ __forceinline__ int xsw(int a) { return a ^ (((a >> 9) & 7) << 4); }

__device__ __forceinline__ ushort4 cvt4(f32x4 v) {
    ushort4 h;
    h.x = f2bf(v[0]); h.y = f2bf(v[1]); h.z = f2bf(v[2]); h.w = f2bf(v[3]);
    return h;
}

// ---------------------------------------------------------------------------
// Prep (16 blocks x 256 thr): per c: G = W W^T + eps I ; chol; Wt = L^{-1} W ;
// store Wt bf16 in MFMA B-fragment order:
//   wfrag[ntile(8)][kk(16)][lane(64)][j(8)]
//   value = Wt[cd = ntile*16 + (lane&15)][r = kk*32 + (lane>>4)*8 + j]
// Also zeroes d_out.
// ---------------------------------------------------------------------------
__global__ void prep_kernel(const float* __restrict__ weight,
                            unsigned short* __restrict__ wfrag,
                            float* __restrict__ out) {
    __shared__ float Wc[NUM_D * RECEPT];
    __shared__ float G[NUM_D][NUM_D];
    __shared__ float Lm[NUM_D][NUM_D];
    const int c = blockIdx.x;
    const int t = threadIdx.x;  // 256 threads

    out[c * 256 + t] = 0.f;
    out[c * 256 + t + 4096] = 0.f;

    const float4* wsrc4 = reinterpret_cast<const float4*>(
        weight + (size_t)c * NUM_D * RECEPT);
    float4* Wc4 = reinterpret_cast<float4*>(Wc);
    #pragma unroll
    for (int i = 0; i < 4; ++i) Wc4[t + i * 256] = wsrc4[t + i * 256];
    __syncthreads();

    if (t < 64) {
        int d = t >> 3, e = t & 7;
        const float4* wd4 = reinterpret_cast<const float4*>(&Wc[d * RECEPT]);
        const float4* we4 = reinterpret_cast<const float4*>(&Wc[e * RECEPT]);
        float s = 0.f;
        #pragma unroll 4
        for (int r4 = 0; r4 < RECEPT / 4; ++r4) {
            float4 a = wd4[r4], bb = we4[r4];
            s += a.x * bb.x + a.y * bb.y + a.z * bb.z + a.w * bb.w;
        }
        if (d == e) s += EPS_V;
        G[d][e] = s;
    }
    __syncthreads();
    if (t == 0) {
        for (int i = 0; i < NUM_D; ++i) {
            float diag = G[i][i];
            for (int k = 0; k < i; ++k) diag -= Lm[i][k] * Lm[i][k];
            float di = sqrtf(diag);
            Lm[i][i] = di;
            float inv = 1.f / di;
            for (int jj = i + 1; jj < NUM_D; ++jj) {
                float s = G[jj][i];
                for (int k = 0; k < i; ++k) s -= Lm[jj][k] * Lm[i][k];
                Lm[jj][i] = s * inv;
            }
        }
    }
    __syncthreads();
    for (int r = t; r < RECEPT; r += 256) {
        float y[NUM_D];
        for (int d = 0; d < NUM_D; ++d) {
            float s = Wc[d * RECEPT + r];
            for (int k = 0; k < d; ++k) s -= Lm[d][k] * y[k];
            y[d] = s / Lm[d][d];
        }
        const int kk = r >> 5;          // 0..15
        const int g  = (r >> 3) & 3;    // k-group within 32
        const int j  = r & 7;
        for (int d = 0; d < NUM_D; ++d) {
            int cd = c * NUM_D + d;
            int ntile = cd >> 4;
            int nl = cd & 15;
            int lane = g * 16 + nl;
            int idx = (((ntile * 16 + kk) * 64) + lane) * 8 + j;
            wfrag[idx] = f2bf(y[d]);
        }
    }
}

// ---------------------------------------------------------------------------
// Main: 1024 blocks (b = bid>>1, half h = bid&1) x 256 thr (4 waves), one
// generation (4 blocks/CU, 16 waves/CU). SPLIT-TILE PIPELINE:
//  issue all 18 nt loads -> counted vmcnt (U half stays in flight) -> write
//  lower half (windows 0-31) -> raw s_barrier (NO vmcnt drain) -> compute
//  mi=0,1 under the streaming upper half -> vmcnt(0) -> write upper ->
//  raw barrier -> compute mi=2,3. K-loop rolled (#pragma unroll 2, no spill).
//  Chunks 2048-2111 are written twice with identical data (benign).
// ---------------------------------------------------------------------------
__global__ __launch_bounds__(256, 4) void main_kernel(
        const float* __restrict__ x,
        const unsigned short* __restrict__ wfrag,
        float* __restrict__ out) {
    __shared__ char lds[XBYTES];
    const int bid = blockIdx.x;
    const int b = bid >> 1;
    const int h = bid & 1;
    const int t = threadIdx.x;
    const int lane = t & 63;
    const int wv = t >> 6;          // 0..3
    const int rl = lane & 15;
    const int gl = lane >> 4;
    const int nt0 = wv * 2;         // this wave's first ntile

    const char* slice = (const char*)(x + (size_t)b * LROW + h * 16384);

#define XLOAD(dst_, i_) \
    dst_ = __builtin_nontemporal_load( \
        reinterpret_cast<const f32x4*>(slice + ((i_) * 256 + t) * 16))
#define XWRITE(src_, i_) \
    *reinterpret_cast<ushort4*>(lds + xsw(((i_) * 256 + t) * 8)) = cvt4(src_)

    // ---- issue phase: all 18 loads (L: 8+mid, U: 8+tail), deepest queue ----
    f32x4 L0, L1, L2, L3, L4, L5, L6, L7, M;
    f32x4 U0, U1, U2, U3, U4, U5, U6, U7, T;
    XLOAD(L0, 0); XLOAD(L1, 1); XLOAD(L2, 2); XLOAD(L3, 3);
    XLOAD(L4, 4); XLOAD(L5, 5); XLOAD(L6, 6); XLOAD(L7, 7);
    if (t < 64)   // mid: chunks 2048-2111 (completes lower window 31)
        M = __builtin_nontemporal_load(
            reinterpret_cast<const f32x4*>(slice + (2048 + t) * 16));
    XLOAD(U0, 8);  XLOAD(U1, 9);  XLOAD(U2, 10); XLOAD(U3, 11);
    XLOAD(U4, 12); XLOAD(U5, 13); XLOAD(U6, 14); XLOAD(U7, 15);
    {   // tail: chunks 4096-4159 (256-elem overlap; wraps for h==1)
        const char* tsrc = h ? (const char*)(x + (size_t)b * LROW)
                             : slice + 65536;
        if (t < 64)
            T = __builtin_nontemporal_load(
                reinterpret_cast<const f32x4*>(tsrc + t * 16));
    }

    // ---- wait for L(+M) only: U(+T) remain in flight across the barrier ----
    if (wv == 0) asm volatile("s_waitcnt vmcnt(9)" ::: "memory");
    else         asm volatile("s_waitcnt vmcnt(8)" ::: "memory");
    __builtin_amdgcn_sched_barrier(0);

    XWRITE(L0, 0); XWRITE(L1, 1); XWRITE(L2, 2); XWRITE(L3, 3);
    XWRITE(L4, 4); XWRITE(L5, 5); XWRITE(L6, 6); XWRITE(L7, 7);
    if (t < 64)
        *reinterpret_cast<ushort4*>(lds + xsw((2048 + t) * 8)) = cvt4(M);

    f32x4 a00 = {0,0,0,0}, a01 = {0,0,0,0};
    f32x4 a10 = {0,0,0,0}, a11 = {0,0,0,0};
    f32x4 a20 = {0,0,0,0}, a21 = {0,0,0,0};
    f32x4 a30 = {0,0,0,0}, a31 = {0,0,0,0};

    asm volatile("s_waitcnt lgkmcnt(0)" ::: "memory");
    __builtin_amdgcn_sched_barrier(0);
    __builtin_amdgcn_s_barrier();          // raw: does NOT drain vmcnt
    __builtin_amdgcn_sched_barrier(0);

    // ---- lower compute (windows 0-31, mi=0,1) under the U stream ----
    {
        const unsigned short* bp0 = wfrag + ((size_t)(nt0 * 16) * 64 + lane) * 8;
        const unsigned short* bp1 = wfrag + ((size_t)((nt0 + 1) * 16) * 64 + lane) * 8;
        const int abase = rl * 512;
        #pragma unroll 2
        for (int kk = 0; kk < 16; ++kk) {
            const int kb = kk * 64 + gl * 16;
            short8 bA = *reinterpret_cast<const short8*>(bp0);
            short8 bB = *reinterpret_cast<const short8*>(bp1);
            bp0 += 512; bp1 += 512;
            short8 af0 = *reinterpret_cast<const short8*>(lds + xsw(abase + kb));
            short8 af1 = *reinterpret_cast<const short8*>(lds + xsw(abase + 8192 + kb));
            a00 = __builtin_amdgcn_mfma_f32_16x16x32_bf16(af0, bA, a00, 0, 0, 0);
            a01 = __builtin_amdgcn_mfma_f32_16x16x32_bf16(af0, bB, a01, 0, 0, 0);
            a10 = __builtin_amdgcn_mfma_f32_16x16x32_bf16(af1, bA, a10, 0, 0, 0);
            a11 = __builtin_amdgcn_mfma_f32_16x16x32_bf16(af1, bB, a11, 0, 0, 0);
        }
    }

    // ---- finish upper stage ----
    asm volatile("s_waitcnt vmcnt(0)" ::: "memory");
    __builtin_amdgcn_sched_barrier(0);
    XWRITE(U0, 8);  XWRITE(U1, 9);  XWRITE(U2, 10); XWRITE(U3, 11);
    XWRITE(U4, 12); XWRITE(U5, 13); XWRITE(U6, 14); XWRITE(U7, 15);
    if (t < 64)
        *reinterpret_cast<ushort4*>(lds + xsw((4096 + t) * 8)) = cvt4(T);
    asm volatile("s_waitcnt lgkmcnt(0)" ::: "memory");
    __builtin_amdgcn_sched_barrier(0);
    __builtin_amdgcn_s_barrier();
    __builtin_amdgcn_sched_barrier(0);

    // ---- upper compute (windows 32-63, mi=2,3); B reloaded (L2-hit) ----
    {
        const unsigned short* bp0 = wfrag + ((size_t)(nt0 * 16) * 64 + lane) * 8;
        const unsigned short* bp1 = wfrag + ((size_t)((nt0 + 1) * 16) * 64 + lane) * 8;
        const int abase = rl * 512;
        #pragma unroll 2
        for (int kk = 0; kk < 16; ++kk) {
            const int kb = kk * 64 + gl * 16;
            short8 bA = *reinterpret_cast<const short8*>(bp0);
            short8 bB = *reinterpret_cast<const short8*>(bp1);
            bp0 += 512; bp1 += 512;
            short8 af2 = *reinterpret_cast<const short8*>(lds + xsw(abase + 16384 + kb));
            short8 af3 = *reinterpret_cast<const short8*>(lds + xsw(abase + 24576 + kb));
            a20 = __builtin_amdgcn_mfma_f32_16x16x32_bf16(af2, bA, a20, 0, 0, 0);
            a21 = __builtin_amdgcn_mfma_f32_16x16x32_bf16(af2, bB, a21, 0, 0, 0);
            a30 = __builtin_amdgcn_mfma_f32_16x16x32_bf16(af3, bA, a30, 0, 0, 0);
            a31 = __builtin_amdgcn_mfma_f32_16x16x32_bf16(af3, bB, a31, 0, 0, 0);
        }
    }
#undef XLOAD
#undef XWRITE

    // epilogue: q = sum over 8 d-columns of P^2 (lane bits 0..2), sqrt,
    // sum over this block's 64 windows, atomics (mean weight 1/128).
#define SQSUM(s_, A_) { \
    _Pragma("unroll") \
    for (int r = 0; r < 4; ++r) { \
        float p = (A_)[r]; float qq = p * p; \
        qq += __shfl_xor(qq, 1); \
        qq += __shfl_xor(qq, 2); \
        qq += __shfl_xor(qq, 4); \
        s_ += sqrtf(qq); } }

    float s0 = 0.f, s1 = 0.f;
    SQSUM(s0, a00) SQSUM(s0, a10) SQSUM(s0, a20) SQSUM(s0, a30)
    SQSUM(s1, a01) SQSUM(s1, a11) SQSUM(s1, a21) SQSUM(s1, a31)
#undef SQSUM
    s0 += __shfl_xor(s0, 16); s0 += __shfl_xor(s0, 32);
    s1 += __shfl_xor(s1, 16); s1 += __shfl_xor(s1, 32);
    if (lane < 16 && (lane & 7) == 0) {
        int c0 = (wv * 32 + lane) >> 3;
        atomicAdd(&out[b * NUM_C + c0], s0 * (1.0f / 128.0f));
        atomicAdd(&out[b * NUM_C + c0 + 2], s1 * (1.0f / 128.0f));
    }
}

extern "C" void kernel_launch(void* const* d_in, const int* in_sizes, int n_in,
                              void* d_out, int out_size, void* d_ws, size_t ws_size,
                              hipStream_t stream) {
    (void)in_sizes; (void)n_in; (void)ws_size; (void)out_size;
    const float* x      = (const float*)d_in[0];
    const float* weight = (const float*)d_in[1];
    float* out = (float*)d_out;
    unsigned short* wfrag = (unsigned short*)d_ws;   // needs 128 KiB scratch

    prep_kernel<<<16, 256, 0, stream>>>(weight, wfrag, out);
    main_kernel<<<1024, 256, 0, stream>>>(x, wfrag, out);
}

// Round 18
// 32.118 us; speedup vs baseline: 1.1006x; 1.1006x over previous
//
#include <hip/hip_runtime.h>
#include <hip/hip_bf16.h>

#define NUM_C  16
#define NUM_D  8
#define RECEPT 512
#define LROW   32768
#define EPS_V  1e-4f

// per-block x slice: 64 windows * 256 stride + 256 overlap = 16640 bf16
// = 33280 B; +headroom for xsw (sets bits 4-6) -> 33536
#define XBYTES 33536

typedef __attribute__((ext_vector_type(8))) short short8;
typedef __attribute__((ext_vector_type(4))) float f32x4;

__device__ __forceinline__ unsigned short f2bf(float f) {
    unsigned int u = __builtin_bit_cast(unsigned int, f);
    u += 0x7fffu + ((u >> 16) & 1u);   // round-to-nearest-even
    return (unsigned short)(u >> 16);
}

// XOR swizzle on byte address in the bf16 x LDS slice (involution; applied on
// both staging writes and A-fragment reads; breaks the 512B window stride).
__device__ __forceinline__ int xsw(int a) { return a ^ (((a >> 9) & 7) << 4); }

__device__ __forceinline__ ushort4 cvt4(f32x4 v) {
    ushort4 h;
    h.x = f2bf(v[0]); h.y = f2bf(v[1]); h.z = f2bf(v[2]); h.w = f2bf(v[3]);
    return h;
}

// streaming read that bypasses cache allocation: system-scope + non-temporal.
// Compiler does NOT track this load's vmcnt -> caller must s_waitcnt manually.
__device__ __forceinline__ f32x4 ldx4_stream(const char* p) {
    f32x4 r;
    asm volatile("global_load_dwordx4 %0, %1, off sc0 sc1 nt"
                 : "=v"(r) : "v"(p));
    return r;
}

// ---------------------------------------------------------------------------
// Prep (16 blocks x 256 thr): per c: G = W W^T + eps I ; chol; Wt = L^{-1} W ;
// store Wt bf16 in MFMA B-fragment order:
//   wfrag[ntile(8)][kk(16)][lane(64)][j(8)]
//   value = Wt[cd = ntile*16 + (lane&15)][r = kk*32 + (lane>>4)*8 + j]
// Also zeroes d_out.
// ---------------------------------------------------------------------------
__global__ void prep_kernel(const float* __restrict__ weight,
                            unsigned short* __restrict__ wfrag,
                            float* __restrict__ out) {
    __shared__ float Wc[NUM_D * RECEPT];
    __shared__ float G[NUM_D][NUM_D];
    __shared__ float Lm[NUM_D][NUM_D];
    const int c = blockIdx.x;
    const int t = threadIdx.x;  // 256 threads

    out[c * 256 + t] = 0.f;
    out[c * 256 + t + 4096] = 0.f;

    const float4* wsrc4 = reinterpret_cast<const float4*>(
        weight + (size_t)c * NUM_D * RECEPT);
    float4* Wc4 = reinterpret_cast<float4*>(Wc);
    #pragma unroll
    for (int i = 0; i < 4; ++i) Wc4[t + i * 256] = wsrc4[t + i * 256];
    __syncthreads();

    if (t < 64) {
        int d = t >> 3, e = t & 7;
        const float4* wd4 = reinterpret_cast<const float4*>(&Wc[d * RECEPT]);
        const float4* we4 = reinterpret_cast<const float4*>(&Wc[e * RECEPT]);
        float s = 0.f;
        #pragma unroll 4
        for (int r4 = 0; r4 < RECEPT / 4; ++r4) {
            float4 a = wd4[r4], bb = we4[r4];
            s += a.x * bb.x + a.y * bb.y + a.z * bb.z + a.w * bb.w;
        }
        if (d == e) s += EPS_V;
        G[d][e] = s;
    }
    __syncthreads();
    if (t == 0) {
        for (int i = 0; i < NUM_D; ++i) {
            float diag = G[i][i];
            for (int k = 0; k < i; ++k) diag -= Lm[i][k] * Lm[i][k];
            float di = sqrtf(diag);
            Lm[i][i] = di;
            float inv = 1.f / di;
            for (int jj = i + 1; jj < NUM_D; ++jj) {
                float s = G[jj][i];
                for (int k = 0; k < i; ++k) s -= Lm[jj][k] * Lm[i][k];
                Lm[jj][i] = s * inv;
            }
        }
    }
    __syncthreads();
    for (int r = t; r < RECEPT; r += 256) {
        float y[NUM_D];
        for (int d = 0; d < NUM_D; ++d) {
            float s = Wc[d * RECEPT + r];
            for (int k = 0; k < d; ++k) s -= Lm[d][k] * y[k];
            y[d] = s / Lm[d][d];
        }
        const int kk = r >> 5;          // 0..15
        const int g  = (r >> 3) & 3;    // k-group within 32
        const int j  = r & 7;
        for (int d = 0; d < NUM_D; ++d) {
            int cd = c * NUM_D + d;
            int ntile = cd >> 4;
            int nl = cd & 15;
            int lane = g * 16 + nl;
            int idx = (((ntile * 16 + kk) * 64) + lane) * 8 + j;
            wfrag[idx] = f2bf(y[d]);
        }
    }
}

// ---------------------------------------------------------------------------
// Main: 1024 blocks (b = bid>>1, half h = bid&1) x 256 thr (4 waves), one
// generation (4 blocks/CU, 16 waves/CU). x staged via CACHE-BYPASS streaming
// loads (sc0 sc1 nt): no L3 allocation -> no dirty-line writebacks of the
// harness's poison data -> read stream at full HBM read rate. Manual counted
// vmcnt (asm loads are invisible to the compiler's waitcnt insertion).
// K-loop ROLLED (#pragma unroll 2) -> no spill (R15/R16-verified).
// ---------------------------------------------------------------------------
__global__ __launch_bounds__(256, 4) void main_kernel(
        const float* __restrict__ x,
        const unsigned short* __restrict__ wfrag,
        float* __restrict__ out) {
    __shared__ char lds[XBYTES];
    const int bid = blockIdx.x;
    const int b = bid >> 1;
    const int h = bid & 1;
    const int t = threadIdx.x;
    const int lane = t & 63;
    const int wv = t >> 6;          // 0..3
    const int rl = lane & 15;
    const int gl = lane >> 4;
    const int nt0 = wv * 2;         // this wave's first ntile

    const char* slice = (const char*)(x + (size_t)b * LROW + h * 16384);

#define XWRITE(src_, i_) \
    *reinterpret_cast<ushort4*>(lds + xsw(((i_) * 256 + t) * 8)) = cvt4(src_)

    // ---- issue ALL 17 streaming loads (uniform per wave: no divergence) ----
    f32x4 L0, L1, L2, L3, L4, L5, L6, L7;
    f32x4 U0, U1, U2, U3, U4, U5, U6, U7, T;
    L0 = ldx4_stream(slice + (0 * 256 + t) * 16);
    L1 = ldx4_stream(slice + (1 * 256 + t) * 16);
    L2 = ldx4_stream(slice + (2 * 256 + t) * 16);
    L3 = ldx4_stream(slice + (3 * 256 + t) * 16);
    L4 = ldx4_stream(slice + (4 * 256 + t) * 16);
    L5 = ldx4_stream(slice + (5 * 256 + t) * 16);
    L6 = ldx4_stream(slice + (6 * 256 + t) * 16);
    L7 = ldx4_stream(slice + (7 * 256 + t) * 16);
    U0 = ldx4_stream(slice + (8 * 256 + t) * 16);
    U1 = ldx4_stream(slice + (9 * 256 + t) * 16);
    U2 = ldx4_stream(slice + (10 * 256 + t) * 16);
    U3 = ldx4_stream(slice + (11 * 256 + t) * 16);
    U4 = ldx4_stream(slice + (12 * 256 + t) * 16);
    U5 = ldx4_stream(slice + (13 * 256 + t) * 16);
    U6 = ldx4_stream(slice + (14 * 256 + t) * 16);
    U7 = ldx4_stream(slice + (15 * 256 + t) * 16);
    {   // tail (256-elem overlap; wraps to row start for h==1); all lanes
        // load (t&63 -> in-bounds), only t<64 writes below.
        const char* tsrc = h ? (const char*)(x + (size_t)b * LROW)
                             : slice + 65536;
        T = ldx4_stream(tsrc + (t & 63) * 16);
    }

    // ---- L batch done (9 still outstanding: U0-7 + T) ----
    asm volatile("s_waitcnt vmcnt(9)" ::: "memory");
    __builtin_amdgcn_sched_barrier(0);
    XWRITE(L0, 0); XWRITE(L1, 1); XWRITE(L2, 2); XWRITE(L3, 3);
    XWRITE(L4, 4); XWRITE(L5, 5); XWRITE(L6, 6); XWRITE(L7, 7);

    // ---- drain the rest ----
    asm volatile("s_waitcnt vmcnt(0)" ::: "memory");
    __builtin_amdgcn_sched_barrier(0);
    XWRITE(U0, 8);  XWRITE(U1, 9);  XWRITE(U2, 10); XWRITE(U3, 11);
    XWRITE(U4, 12); XWRITE(U5, 13); XWRITE(U6, 14); XWRITE(U7, 15);
    if (t < 64)
        *reinterpret_cast<ushort4*>(lds + xsw((4096 + t) * 8)) = cvt4(T);
#undef XWRITE

    f32x4 a00 = {0,0,0,0}, a01 = {0,0,0,0};
    f32x4 a10 = {0,0,0,0}, a11 = {0,0,0,0};
    f32x4 a20 = {0,0,0,0}, a21 = {0,0,0,0};
    f32x4 a30 = {0,0,0,0}, a31 = {0,0,0,0};

    __syncthreads();        // x slice visible to all waves

    // per-wave B pointers; stride per kk = 64 lanes * 8 shorts = 512 elems
    const unsigned short* bptr0 = wfrag + ((size_t)(nt0 * 16) * 64 + lane) * 8;
    const unsigned short* bptr1 = wfrag + ((size_t)((nt0 + 1) * 16) * 64 + lane) * 8;
    const int abase = rl * 512;    // byte base of this lane's window row 0

    #pragma unroll 2
    for (int kk = 0; kk < 16; ++kk) {
        const int kb = kk * 64 + gl * 16;      // byte offset along k
        short8 bA = *reinterpret_cast<const short8*>(bptr0);
        short8 bB = *reinterpret_cast<const short8*>(bptr1);
        bptr0 += 512; bptr1 += 512;
        short8 af0 = *reinterpret_cast<const short8*>(lds + xsw(abase + kb));
        short8 af1 = *reinterpret_cast<const short8*>(lds + xsw(abase + 8192 + kb));
        short8 af2 = *reinterpret_cast<const short8*>(lds + xsw(abase + 16384 + kb));
        short8 af3 = *reinterpret_cast<const short8*>(lds + xsw(abase + 24576 + kb));
        a00 = __builtin_amdgcn_mfma_f32_16x16x32_bf16(af0, bA, a00, 0, 0, 0);
        a01 = __builtin_amdgcn_mfma_f32_16x16x32_bf16(af0, bB, a01, 0, 0, 0);
        a10 = __builtin_amdgcn_mfma_f32_16x16x32_bf16(af1, bA, a10, 0, 0, 0);
        a11 = __builtin_amdgcn_mfma_f32_16x16x32_bf16(af1, bB, a11, 0, 0, 0);
        a20 = __builtin_amdgcn_mfma_f32_16x16x32_bf16(af2, bA, a20, 0, 0, 0);
        a21 = __builtin_amdgcn_mfma_f32_16x16x32_bf16(af2, bB, a21, 0, 0, 0);
        a30 = __builtin_amdgcn_mfma_f32_16x16x32_bf16(af3, bA, a30, 0, 0, 0);
        a31 = __builtin_amdgcn_mfma_f32_16x16x32_bf16(af3, bB, a31, 0, 0, 0);
    }

    // epilogue: q = sum over 8 d-columns of P^2 (lane bits 0..2), sqrt,
    // sum over this block's 64 windows, atomics (mean weight 1/128).
#define SQSUM(s_, A_) { \
    _Pragma("unroll") \
    for (int r = 0; r < 4; ++r) { \
        float p = (A_)[r]; float qq = p * p; \
        qq += __shfl_xor(qq, 1); \
        qq += __shfl_xor(qq, 2); \
        qq += __shfl_xor(qq, 4); \
        s_ += sqrtf(qq); } }

    float s0 = 0.f, s1 = 0.f;
    SQSUM(s0, a00) SQSUM(s0, a10) SQSUM(s0, a20) SQSUM(s0, a30)
    SQSUM(s1, a01) SQSUM(s1, a11) SQSUM(s1, a21) SQSUM(s1, a31)
#undef SQSUM
    s0 += __shfl_xor(s0, 16); s0 += __shfl_xor(s0, 32);
    s1 += __shfl_xor(s1, 16); s1 += __shfl_xor(s1, 32);
    if (lane < 16 && (lane & 7) == 0) {
        int c0 = (wv * 32 + lane) >> 3;
        atomicAdd(&out[b * NUM_C + c0], s0 * (1.0f / 128.0f));
        atomicAdd(&out[b * NUM_C + c0 + 2], s1 * (1.0f / 128.0f));
    }
}

extern "C" void kernel_launch(void* const* d_in, const int* in_sizes, int n_in,
                              void* d_out, int out_size, void* d_ws, size_t ws_size,
                              hipStream_t stream) {
    (void)in_sizes; (void)n_in; (void)ws_size; (void)out_size;
    const float* x      = (const float*)d_in[0];
    const float* weight = (const float*)d_in[1];
    float* out = (float*)d_out;
    unsigned short* wfrag = (unsigned short*)d_ws;   // needs 128 KiB scratch

    prep_kernel<<<16, 256, 0, stream>>>(weight, wfrag, out);
    main_kernel<<<1024, 256, 0, stream>>>(x, wfrag, out);
}